// Round 1
// baseline (24.750 us; speedup 1.0000x reference)
//
#include <hip/hip_runtime.h>

#define SMOOTHF 0.001f
#define DICE_WF 0.8f

constexpr int N_B = 16, N_C = 3, N_H = 512, N_W = 512;
constexpr int SLICES   = N_B * N_C;          // 48
constexpr int ELEMS    = N_H * N_W;          // 262144 elements per (b,c) slice
constexpr int TPB      = 256;
constexpr int BPS      = 32;                 // blocks per slice
constexpr int V4_SLICE = ELEMS / 4;          // 65536 float4 per slice
constexpr int V4_BLOCK = V4_SLICE / BPS;     // 2048 float4 per block
constexpr int V4_THREAD = V4_BLOCK / TPB;    // 8 float4 per thread
constexpr int WS_FLOATS = SLICES * BPS * 5;  // 7680 floats = 30 KB scratch

struct Acc { float sp, it, cp, s1, s0; };

__device__ __forceinline__ void acc1(float x, float t, Acc& a) {
    float p  = 1.0f / (1.0f + __expf(-x));   // sigmoid
    float d  = x - t;
    float d2 = d * d;
    bool pos = t > 0.0f;                     // targets are binary {0,1}
    a.sp += p;
    a.it += pos ? p    : 0.0f;
    a.cp += pos ? 1.0f : 0.0f;
    a.s1 += pos ? d2   : 0.0f;
    a.s0 += pos ? 0.0f : d2;
}

__device__ __forceinline__ void waveReduce5(Acc& a) {
    #pragma unroll
    for (int off = 32; off > 0; off >>= 1) {
        a.sp += __shfl_down(a.sp, off, 64);
        a.it += __shfl_down(a.it, off, 64);
        a.cp += __shfl_down(a.cp, off, 64);
        a.s1 += __shfl_down(a.s1, off, 64);
        a.s0 += __shfl_down(a.s0, off, 64);
    }
}

// Stage 1: each block reduces a contiguous 8192-element chunk of one slice,
// writes 5 partial sums to ws[blk*5 .. blk*5+4]. Fully deterministic.
__global__ __launch_bounds__(TPB) void stage1(const float4* __restrict__ lg,
                                              const float4* __restrict__ tg,
                                              float* __restrict__ ws) {
    const int blk  = blockIdx.x;
    const int base = blk * V4_BLOCK + (int)threadIdx.x;
    Acc a{0.f, 0.f, 0.f, 0.f, 0.f};
    #pragma unroll
    for (int k = 0; k < V4_THREAD; ++k) {
        float4 x4 = lg[base + k * TPB];
        float4 t4 = tg[base + k * TPB];
        acc1(x4.x, t4.x, a); acc1(x4.y, t4.y, a);
        acc1(x4.z, t4.z, a); acc1(x4.w, t4.w, a);
    }
    waveReduce5(a);
    __shared__ float red[TPB / 64][5];
    const int wave = threadIdx.x >> 6;
    if ((threadIdx.x & 63) == 0) {
        red[wave][0] = a.sp; red[wave][1] = a.it; red[wave][2] = a.cp;
        red[wave][3] = a.s1; red[wave][4] = a.s0;
    }
    __syncthreads();
    if (threadIdx.x < 5) {
        float v = 0.f;
        #pragma unroll
        for (int w = 0; w < TPB / 64; ++w) v += red[w][threadIdx.x];
        ws[blk * 5 + threadIdx.x] = v;
    }
}

// Stage 2: one wave. Thread t < 48 folds its slice's 32 partial records,
// computes dice + mse for that (b,c); wave-reduce; lane 0 writes the scalar.
__global__ __launch_bounds__(64) void stage2(const float* __restrict__ ws,
                                             float* __restrict__ out) {
    const int t = threadIdx.x;
    float dice = 0.f, mse = 0.f;
    if (t < SLICES) {
        float sp = 0.f, it = 0.f, cp = 0.f, s1 = 0.f, s0 = 0.f;
        for (int b = 0; b < BPS; ++b) {
            const float* p = ws + (t * BPS + b) * 5;
            sp += p[0]; it += p[1]; cp += p[2]; s1 += p[3]; s0 += p[4];
        }
        // sum_t == cnt_pos for binary targets; union = sum_p + sum_t
        dice = (2.0f * it + SMOOTHF) / (sp + cp + SMOOTHF);
        float cn = (float)ELEMS - cp;
        float mp = (cp > 0.f) ? s1 / fmaxf(cp, 1.f) : 0.f;
        float mn = (cn > 0.f) ? s0 / fmaxf(cn, 1.f) : 0.f;
        mse = mp + mn;
    }
    #pragma unroll
    for (int off = 32; off > 0; off >>= 1) {
        dice += __shfl_down(dice, off, 64);
        mse  += __shfl_down(mse,  off, 64);
    }
    if (t == 0) {
        float dice_loss = 1.0f - dice / (float)SLICES;  // == sum_c(1-mean_b)/C
        float mse_loss  = mse / (float)SLICES;          // == sum/(B*C)
        out[0] = DICE_WF * dice_loss + (1.0f - DICE_WF) * mse_loss;
    }
}

// ---- Fallback path (only if ws is too small): fused per-slice kernel ----
__global__ void init_out(float* out) { out[0] = DICE_WF; }

__global__ __launch_bounds__(1024) void fused_slice(const float4* __restrict__ lg,
                                                    const float4* __restrict__ tg,
                                                    float* __restrict__ out) {
    const int s    = blockIdx.x;
    const int base = s * V4_SLICE + (int)threadIdx.x;
    Acc a{0.f, 0.f, 0.f, 0.f, 0.f};
    for (int k = 0; k < V4_SLICE / 1024; ++k) {
        float4 x4 = lg[base + k * 1024];
        float4 t4 = tg[base + k * 1024];
        acc1(x4.x, t4.x, a); acc1(x4.y, t4.y, a);
        acc1(x4.z, t4.z, a); acc1(x4.w, t4.w, a);
    }
    waveReduce5(a);
    __shared__ float red[16][5];
    const int wave = threadIdx.x >> 6;
    if ((threadIdx.x & 63) == 0) {
        red[wave][0] = a.sp; red[wave][1] = a.it; red[wave][2] = a.cp;
        red[wave][3] = a.s1; red[wave][4] = a.s0;
    }
    __syncthreads();
    if (threadIdx.x == 0) {
        float sp = 0.f, it = 0.f, cp = 0.f, s1 = 0.f, s0 = 0.f;
        for (int w = 0; w < 16; ++w) {
            sp += red[w][0]; it += red[w][1]; cp += red[w][2];
            s1 += red[w][3]; s0 += red[w][4];
        }
        float dice = (2.0f * it + SMOOTHF) / (sp + cp + SMOOTHF);
        float cn = (float)ELEMS - cp;
        float mp = (cp > 0.f) ? s1 / fmaxf(cp, 1.f) : 0.f;
        float mn = (cn > 0.f) ? s0 / fmaxf(cn, 1.f) : 0.f;
        float term = (-DICE_WF * dice + (1.0f - DICE_WF) * (mp + mn)) / (float)SLICES;
        atomicAdd(out, term);
    }
}

extern "C" void kernel_launch(void* const* d_in, const int* in_sizes, int n_in,
                              void* d_out, int out_size, void* d_ws, size_t ws_size,
                              hipStream_t stream) {
    const float4* lg = (const float4*)d_in[0];
    const float4* tg = (const float4*)d_in[1];
    float* out = (float*)d_out;
    if (ws_size >= WS_FLOATS * sizeof(float)) {
        float* ws = (float*)d_ws;
        stage1<<<SLICES * BPS, TPB, 0, stream>>>(lg, tg, ws);
        stage2<<<1, 64, 0, stream>>>(ws, out);
    } else {
        init_out<<<1, 1, 0, stream>>>(out);
        fused_slice<<<SLICES, 1024, 0, stream>>>(lg, tg, out);
    }
}

// Round 2
// 23.132 us; speedup vs baseline: 1.0700x; 1.0700x over previous
//
#include <hip/hip_runtime.h>

#define SMOOTHF 0.001f
#define DICE_WF 0.8f

constexpr int N_B = 16, N_C = 3, N_H = 512, N_W = 512;
constexpr int SLICES    = N_B * N_C;          // 48
constexpr int ELEMS     = N_H * N_W;          // 262144 elements per (b,c) slice
constexpr int TPB       = 256;
constexpr int BPS       = 32;                 // blocks per slice
constexpr int NBLK      = SLICES * BPS;       // 1536 stage1 blocks
constexpr int V4_SLICE  = ELEMS / 4;          // 65536 float4 per slice
constexpr int V4_BLOCK  = V4_SLICE / BPS;     // 2048 float4 per block
constexpr int V4_THREAD = V4_BLOCK / TPB;     // 8 float4 per thread
constexpr int WS_FLOATS = 5 * NBLK;           // SoA: ws[comp][1536]

// Five linear accumulators (targets are exactly {0,1}):
//   sp = Σ sigmoid(x)         pt = Σ sigmoid(x)·t     st = Σ t
//   sd = Σ (x−t)²             sdt = Σ (x−t)²·t
// Derived later: inter = pt, cnt_pos = st, sse_pos = sdt, sse_neg = sd − sdt.
struct Acc { float sp, pt, st, sd, sdt; };

__device__ __forceinline__ void acc1(float x, float t, Acc& a) {
    float e  = __expf(-x);                     // v_mul + v_exp
    float p  = __builtin_amdgcn_rcpf(1.0f + e); // v_rcp (not the div sequence)
    float d  = x - t;
    float d2 = d * d;
    a.sp += p;
    a.pt  = fmaf(p, t, a.pt);
    a.st += t;
    a.sd += d2;
    a.sdt = fmaf(d2, t, a.sdt);
}

__device__ __forceinline__ void waveReduce5(Acc& a) {
    #pragma unroll
    for (int off = 32; off > 0; off >>= 1) {
        a.sp  += __shfl_down(a.sp,  off, 64);
        a.pt  += __shfl_down(a.pt,  off, 64);
        a.st  += __shfl_down(a.st,  off, 64);
        a.sd  += __shfl_down(a.sd,  off, 64);
        a.sdt += __shfl_down(a.sdt, off, 64);
    }
}

// Stage 1: block reduces a contiguous 8192-elem chunk of one slice; writes
// 5 partials SoA: ws[c*NBLK + blockIdx.x]. Deterministic.
__global__ __launch_bounds__(TPB) void stage1(const float4* __restrict__ lg,
                                              const float4* __restrict__ tg,
                                              float* __restrict__ ws) {
    const int blk  = blockIdx.x;
    const int base = blk * V4_BLOCK + (int)threadIdx.x;
    Acc a{0.f, 0.f, 0.f, 0.f, 0.f};
    #pragma unroll
    for (int k = 0; k < V4_THREAD; ++k) {
        float4 x4 = lg[base + k * TPB];
        float4 t4 = tg[base + k * TPB];
        acc1(x4.x, t4.x, a); acc1(x4.y, t4.y, a);
        acc1(x4.z, t4.z, a); acc1(x4.w, t4.w, a);
    }
    waveReduce5(a);
    __shared__ float red[TPB / 64][5];
    const int wave = threadIdx.x >> 6;
    if ((threadIdx.x & 63) == 0) {
        red[wave][0] = a.sp; red[wave][1] = a.pt; red[wave][2] = a.st;
        red[wave][3] = a.sd; red[wave][4] = a.sdt;
    }
    __syncthreads();
    if (threadIdx.x < 5) {
        float v = 0.f;
        #pragma unroll
        for (int w = 0; w < TPB / 64; ++w) v += red[w][threadIdx.x];
        ws[threadIdx.x * NBLK + blk] = v;
    }
}

// Stage 2: one wave. Thread t < 48 folds its slice's 32 partials per
// component (float4-contiguous in SoA), computes dice + mse; wave-reduce.
__global__ __launch_bounds__(64) void stage2(const float* __restrict__ ws,
                                             float* __restrict__ out) {
    const int t = threadIdx.x;
    float dice = 0.f, mse = 0.f;
    if (t < SLICES) {
        float c[5];
        #pragma unroll
        for (int comp = 0; comp < 5; ++comp) {
            const float4* p = (const float4*)(ws + comp * NBLK + t * BPS);
            float4 s = {0.f, 0.f, 0.f, 0.f};
            #pragma unroll
            for (int k = 0; k < BPS / 4; ++k) {
                float4 v = p[k];
                s.x += v.x; s.y += v.y; s.z += v.z; s.w += v.w;
            }
            c[comp] = (s.x + s.y) + (s.z + s.w);
        }
        float sp = c[0], pt = c[1], st = c[2], sd = c[3], sdt = c[4];
        // union = Σp + Σt ; inter = Σp·t ; cnt_pos = Σt (binary targets)
        dice = (2.0f * pt + SMOOTHF) / (sp + st + SMOOTHF);
        float cp = st;
        float cn = (float)ELEMS - cp;
        float s1 = sdt, s0 = sd - sdt;
        float mp = (cp > 0.f) ? s1 / fmaxf(cp, 1.f) : 0.f;
        float mn = (cn > 0.f) ? s0 / fmaxf(cn, 1.f) : 0.f;
        mse = mp + mn;
    }
    #pragma unroll
    for (int off = 32; off > 0; off >>= 1) {
        dice += __shfl_down(dice, off, 64);
        mse  += __shfl_down(mse,  off, 64);
    }
    if (t == 0) {
        float dice_loss = 1.0f - dice / (float)SLICES;  // == sum_c(1-mean_b)/C
        float mse_loss  = mse / (float)SLICES;          // == sum/(B*C)
        out[0] = DICE_WF * dice_loss + (1.0f - DICE_WF) * mse_loss;
    }
}

extern "C" void kernel_launch(void* const* d_in, const int* in_sizes, int n_in,
                              void* d_out, int out_size, void* d_ws, size_t ws_size,
                              hipStream_t stream) {
    const float4* lg = (const float4*)d_in[0];
    const float4* tg = (const float4*)d_in[1];
    float* out = (float*)d_out;
    float* ws  = (float*)d_ws;   // needs 30 KB; harness scratch is far larger
    stage1<<<NBLK, TPB, 0, stream>>>(lg, tg, ws);
    stage2<<<1, 64, 0, stream>>>(ws, out);
}